// Round 4
// baseline (87.570 us; speedup 1.0000x reference)
//
#include <hip/hip_runtime.h>

#define MARGIN 0.2f
#define BATCH 512
#define FEAT 256
#define NF4 (FEAT / 4)   // 64 float4 per row

// ---------------------------------------------------------------------------
// Two anchors per block, 1024 threads: a = tid>>9 (0/1), j = tid&511.
// Each thread does exactly the (passing) R3 per-thread work for (i=2*blk+a, j);
// x_j is read by threads tid and tid+512 -> second read is an L1 hit, so L2
// traffic halves vs R3 (268 -> ~134 MB). 256 blocks = 1 block/CU, 16 waves/CU.
// Waves are anchor-pure (each 64-lane wave lies inside one 512-thread half),
// so ballot compaction is per-anchor-correct unchanged.
// partial[blk] = (hinge_sum, cp0*cn0 + cp1*cn1); every slot written every
// call -> safe against the 0xAA re-poison of d_ws.
// ---------------------------------------------------------------------------
__global__ __launch_bounds__(1024) void anchor2_kernel(const float* __restrict__ X,
                                                       const int* __restrict__ y,
                                                       float2* __restrict__ partial) {
    __shared__ float4 xi_s[2][NF4];       // the two anchor rows
    __shared__ float  pos_s[2][BATCH];
    __shared__ float  neg_s[2][BATCH];
    __shared__ int    cnt_s[4];           // {cp0, cn0, cp1, cn1}
    __shared__ float  wsum[16];

    const int tid = threadIdx.x;
    const int a   = tid >> 9;             // anchor slot 0/1
    const int j   = tid & 511;            // column
    const int i   = (blockIdx.x << 1) | a;
    const float4* X4 = (const float4*)X;

    // stage both anchor rows: 128 float4 loads, coalesced
    if (tid < 2 * NF4)
        ((float4*)xi_s)[tid] = X4[((blockIdx.x << 1) + (tid >> 6)) * NF4 + (tid & 63)];
    if (tid < 4) cnt_s[tid] = 0;
    __syncthreads();

    // --- squared distance d(i, j) ---
    float s = 0.f;
    {
        const float4* xj = X4 + (size_t)j * NF4;
#pragma unroll 4
        for (int f = 0; f < NF4; ++f) {
            float4 av = xi_s[a][f];   // LDS broadcast within each half
            float4 bv = xj[f];        // tid & tid+512 share this line via L1
            float d0 = av.x - bv.x, d1 = av.y - bv.y;
            float d2 = av.z - bv.z, d3 = av.w - bv.w;
            s = fmaf(d0, d0, s); s = fmaf(d1, d1, s);
            s = fmaf(d2, d2, s); s = fmaf(d3, d3, s);
        }
    }

    const int yi = y[i];
    const int yj = y[j];
    const bool is_pos = (yj == yi) && (j != i);
    const bool is_neg = (yj != yi);

    // --- ballot compaction into this anchor's lists ---
    const int lane = tid & 63;
    const unsigned long long lt = (((unsigned long long)1) << lane) - 1;
    unsigned long long mp = __ballot(is_pos);
    unsigned long long mn = __ballot(is_neg);
    int basep = 0, basen = 0;
    if (lane == 0) {
        basep = atomicAdd(&cnt_s[a * 2 + 0], __popcll(mp));
        basen = atomicAdd(&cnt_s[a * 2 + 1], __popcll(mn));
    }
    basep = __shfl(basep, 0);
    basen = __shfl(basen, 0);
    if (is_pos) pos_s[a][basep + __popcll(mp & lt)] = s + MARGIN;
    if (is_neg) neg_s[a][basen + __popcll(mn & lt)] = s;
    __syncthreads();

    const int cp = cnt_s[a * 2 + 0], cn = cnt_s[a * 2 + 1];

    // --- dense hinge over this anchor's lists (512 threads per anchor) ---
    float hs = 0.f;
    for (int jj = 0; jj < cp; ++jj) {       // ~8 iterations, wave-uniform
        float dp = pos_s[a][jj];            // LDS broadcast
        for (int k = j; k < cn; k += 512)   // consecutive -> conflict-free
            hs += fmaxf(dp - neg_s[a][k], 0.f);
    }

    // --- block reduction: wave shuffle + LDS across 16 waves ---
#pragma unroll
    for (int off = 32; off > 0; off >>= 1) hs += __shfl_down(hs, off);
    if (lane == 0) wsum[tid >> 6] = hs;
    __syncthreads();
    if (tid == 0) {
        float bs = 0.f;
#pragma unroll
        for (int w = 0; w < 16; ++w) bs += wsum[w];
        int cnt = cnt_s[0] * cnt_s[1] + cnt_s[2] * cnt_s[3];  // < 2^24, exact
        partial[blockIdx.x] = make_float2(bs, (float)cnt);
    }
}

// ---------------------------------------------------------------------------
// Final reduction over 256 (sum, count) pairs + divide.
// ---------------------------------------------------------------------------
__global__ __launch_bounds__(256) void reduce_kernel(const float2* __restrict__ partial,
                                                     float* __restrict__ out) {
    __shared__ float ws[4], wc[4];
    const int tid = threadIdx.x;
    float2 v = partial[tid];
    float s = v.x, c = v.y;
#pragma unroll
    for (int off = 32; off > 0; off >>= 1) {
        s += __shfl_down(s, off);
        c += __shfl_down(c, off);
    }
    if ((tid & 63) == 0) { ws[tid >> 6] = s; wc[tid >> 6] = c; }
    __syncthreads();
    if (tid == 0) {
        float st = 0.f, ct = 0.f;
#pragma unroll
        for (int w = 0; w < 4; ++w) { st += ws[w]; ct += wc[w]; }
        out[0] = st / ct;
    }
}

extern "C" void kernel_launch(void* const* d_in, const int* in_sizes, int n_in,
                              void* d_out, int out_size, void* d_ws, size_t ws_size,
                              hipStream_t stream) {
    const float* X = (const float*)d_in[0];   // [512, 256] fp32
    const int*   y = (const int*)d_in[1];     // [512] labels
    float* out = (float*)d_out;               // scalar fp32
    float2* partial = (float2*)d_ws;          // 256 float2 = 2 KB

    anchor2_kernel<<<BATCH / 2, 1024, 0, stream>>>(X, y, partial);
    reduce_kernel<<<1, 256, 0, stream>>>(partial, out);
}